// Round 2
// 114.297 us; speedup vs baseline: 1.0483x; 1.0483x over previous
//
#include <hip/hip_runtime.h>
#include <math.h>

#define BLK 256

typedef __attribute__((ext_vector_type(8))) short s16x8;
typedef __attribute__((ext_vector_type(16))) float f32x16;

__device__ __forceinline__ float b2f(unsigned short h) {
    union { unsigned u; float f; } x; x.u = ((unsigned)h) << 16; return x.f;
}
__device__ __forceinline__ unsigned short f2b(float f) {
    union { float f; unsigned u; } x; x.f = f;
    unsigned r = x.u + 0x7fffu + ((x.u >> 16) & 1u);
    return (unsigned short)(r >> 16);
}

#define SITE(i, j) (peps + (size_t)((i) * 4 + (j)) * 2 * 1296)

// ======================= MFMA config (proven layout, verbatim) ==============
// A=env (lane->m), B=tile (lane->n via rows nt*4+col), C/D: col(lane)=n,
// row=(reg&3)+8*(reg>>2)+4*(lane>>5) [m74/m101]. Wave w owns Mtiles {w,w+4}
// (w<3) / {3}; Mtile6 base 184, dedup keeps m>=192. Ntile1 keeps n>=32.
// Single batch per block (mechanical slot-removal from the proven 2-slot
// kernel; per-batch math graph unchanged). launch_bounds(...,3) caps unified
// VGPR+AGPR at 170 (no spill; round-1's (.,4)=128-reg cap forced acc spills).

#define MFMA_PHASE(NKB, NNT, TB, TSTR) do {                                    \
    s16x8 _bf[NNT][NKB];                                                       \
    _Pragma("unroll") for (int nt = 0; nt < NNT; ++nt)                         \
    _Pragma("unroll") for (int kb = 0; kb < NKB; ++kb)                         \
        _bf[nt][kb] = *(const s16x8*)&(TB)[(nt*4 + col)*(TSTR) + kb*16 + q*8]; \
    _Pragma("unroll") for (int i = 0; i < 2; ++i) {                            \
        if (i < nmt) {                                                         \
            int mt = wid + 4*i; int m0 = (mt == 6) ? 184 : mt*32;              \
            s16x8 _av[NKB];                                                    \
            _Pragma("unroll") for (int kb = 0; kb < NKB; ++kb)                 \
                _av[kb] = *(const s16x8*)&Ebuf[(m0 + col)*56 + kb*16 + q*8];   \
            _Pragma("unroll") for (int nt = 0; nt < NNT; ++nt)                 \
            _Pragma("unroll") for (int kb = 0; kb < NKB; ++kb)                 \
                acc[i][nt] = __builtin_amdgcn_mfma_f32_32x32x16_bf16(          \
                    _av[kb], _bf[nt][kb], acc[i][nt], 0, 0, 0);                \
        } } } while (0)

// PUT uses (m, n, v) and may use EbS / T1S.
#define SCATTER(NNT, NLIM, PUT) do {                                           \
    unsigned short* EbS = Ebuf;                                                \
    float* T1S = (float*)Ebuf; (void)EbS; (void)T1S;                           \
    _Pragma("unroll") for (int i = 0; i < 2; ++i) {                            \
      if (i < nmt) {                                                           \
        int mt = wid + 4*i; int m0 = (mt == 6) ? 184 : mt*32;                  \
        _Pragma("unroll") for (int nt = 0; nt < NNT; ++nt) {                   \
            int n = nt*4 + col;                                                \
            if ((NNT == 2 && nt == 1 && n < 32) || n >= NLIM) continue;        \
            _Pragma("unroll") for (int r = 0; r < 16; ++r) {                   \
                int m = m0 + (r&3) + 8*(r>>2) + 4*q;                           \
                if (mt == 6 && m < 192) continue;                              \
                float v = acc[i][nt][r];                                       \
                PUT;                                                           \
            } } } } } while (0)

#define ACC0() do {                                                            \
    _Pragma("unroll") for (int i = 0; i < 2; ++i)                              \
    _Pragma("unroll") for (int nt = 0; nt < 2; ++nt)                           \
    _Pragma("unroll") for (int r = 0; r < 16; ++r) acc[i][nt][r] = 0.f;        \
    } while (0)

__global__ __launch_bounds__(BLK, 3)
void peps_fused(const float* __restrict__ inputs,
                const float* __restrict__ peps,
                const float* __restrict__ pepsc,
                float* __restrict__ out)
{
    // LDS ~38.6 KB; occupancy expected reg-limited at 3 blocks/CU.
    __shared__ __align__(16) unsigned short Ebuf[216 * 56];  // env bf16 [m][56]
    __shared__ __align__(16) unsigned short TA[36 * 56];     // rotating big tile
    __shared__ __align__(16) unsigned short TBt[36 * 56];    // EBT tile
    __shared__ __align__(16) unsigned short Tk6[2 * 36 * 16];// T10, T20
    __shared__ __align__(16) float CTf[936];                 // chain tiles / T13 / NT
    __shared__ float xs[32];
    __shared__ float red[52];

    const int b0  = blockIdx.x;
    const int tid = threadIdx.x;
    const int lid = tid & 63;
    const int q   = lid >> 5;
    const int col = lid & 31;
    const int wid = tid >> 6;
    const int nmt = (wid < 3) ? 2 : 1;

    f32x16 acc[2][2];

    // ---- P0: zero Ebuf (k-pads stay 0 forever), load x (scaled by 100:
    //          constant rescale, absorbed by the final normalization).
    {
        uint4* ez = (uint4*)&Ebuf[0];
        const uint4 z = make_uint4(0u, 0u, 0u, 0u);
        for (int i2 = tid; i2 < 1512; i2 += BLK) ez[i2] = z;
        if (tid < 32) xs[tid] = inputs[b0 * 32 + tid] * 100.0f;
    }
    __syncthreads();

    // ---- P1: ALL early weight gathers ------------------------------------
    for (int idx = tid; idx < 216; idx += BLK) {
        int x = idx/36, d = (idx/6)%6, r = idx%6;
        int g0 = x + d*6 + r*36, g3 = x + d*216 + r*36;
        float a, c;
        a = SITE(0,1)[g0]; c = SITE(0,1)[g0+1296];
        CTf[idx]       = xs[2]  * a + xs[3]  * c;
        a = SITE(0,2)[g0]; c = SITE(0,2)[g0+1296];
        CTf[216 + idx] = xs[4]  * a + xs[5]  * c;
        a = SITE(3,1)[g3]; c = SITE(3,1)[g3+1296];
        CTf[432 + idx] = xs[26] * a + xs[27] * c;
        a = SITE(3,2)[g3]; c = SITE(3,2)[g3+1296];
        CTf[648 + idx] = xs[28] * a + xs[29] * c;
    }
    for (int idx = tid; idx < 36; idx += BLK) {
        int x = idx/6, d = idx%6;
        float a, c;
        a = SITE(0,3)[x + d*6];   c = SITE(0,3)[x + d*6 + 1296];
        CTf[864 + idx] = xs[6]  * a + xs[7]  * c;
        a = SITE(3,3)[x + d*216]; c = SITE(3,3)[x + d*216 + 1296];
        CTf[900 + idx] = xs[30] * a + xs[31] * c;
        int u = x, r = d;
        float a0 = SITE(0,0)[r*36 + u*6],   c0 = SITE(0,0)[r*36 + u*6 + 1296];
        float a3 = SITE(3,0)[u*216 + r*36], c3 = SITE(3,0)[u*216 + r*36 + 1296];
        Ebuf[u*56 + 6  + r] = f2b(xs[0]  * a0 + xs[1]  * c0);
        Ebuf[u*56 + 18 + r] = f2b(xs[24] * a3 + xs[25] * c3);
    }
    {   // T10 / T20 (K6 tiles [36][16], k>=6 zero)
        const float *s10 = SITE(1,0), *s20 = SITE(2,0);
        for (int idx = tid; idx < 576; idx += BLK) {
            int n = idx/16, k = idx%16;
            float v00 = 0.f, v10 = 0.f;
            if (k < 6) {
                int g = k*216 + (n/6)*6 + (n%6)*36;
                float a = s10[g], c = s10[g+1296];
                v00 = xs[8]  * a + xs[9]  * c;
                a = s20[g]; c = s20[g+1296];
                v10 = xs[16] * a + xs[17] * c;
            }
            Tk6[n*16 + k]       = f2b(v00);
            Tk6[576 + n*16 + k] = f2b(v10);
        }
    }
    {   // T11 -> TA ([36][48 valid], k>=36 zero)
        const float* s = SITE(1,1);
        for (int idx = tid; idx < 1728; idx += BLK) {
            int n = idx/48, k = idx%48;
            float v0 = 0.f;
            if (k < 36) {
                int g = (k/6)*216 + (k%6) + (n/6)*6 + (n%6)*36;
                float a = s[g], c = s[g+1296];
                v0 = xs[10] * a + xs[11] * c;
            }
            TA[n*56 + k] = f2b(v0);
        }
    }
    for (int idx = tid; idx < 432; idx += BLK) {   // TBt k-pads 36..47 zero
        int n = idx/12, k = 36 + idx%12;
        TBt[n*56 + k] = 0;
    }
    __syncthreads();

    // ---- P2: chain step1 (M=6) -------------------------------------------
    for (int t2 = tid; t2 < 216; t2 += BLK) {
        int m = t2/36, n = t2%36;
        float a0 = 0.f, a3 = 0.f;
        #pragma unroll
        for (int k = 0; k < 6; ++k) {
            a0 = fmaf(b2f(Ebuf[m*56 + 6  + k]), CTf[k*36 + n],       a0);
            a3 = fmaf(b2f(Ebuf[m*56 + 18 + k]), CTf[432 + k*36 + n], a3);
        }
        int o = (m*6 + n/6)*56 + n%6;
        Ebuf[o + 12] = f2b(a0);
        Ebuf[o + 24] = f2b(a3);
    }
    __syncthreads();

    // ---- P3: chain step2 (M=36) ------------------------------------------
    for (int t2 = tid; t2 < 1296; t2 += BLK) {
        int m = t2/36, n = t2%36;
        float a0 = 0.f, a3 = 0.f;
        #pragma unroll
        for (int k = 0; k < 6; ++k) {
            a0 = fmaf(b2f(Ebuf[m*56 + 12 + k]), CTf[216 + k*36 + n], a0);
            a3 = fmaf(b2f(Ebuf[m*56 + 24 + k]), CTf[648 + k*36 + n], a3);
        }
        int o = (m*6 + n/6)*56 + n%6;
        Ebuf[o + 6]  = f2b(a0);
        Ebuf[o + 18] = f2b(a3);
    }
    __syncthreads();

    // ---- P4: chain tails: band6 -> E0 (cols 0..5); band18 -> EBT bf16 ----
    for (int t2 = tid; t2 < 1296; t2 += BLK) {
        int m = t2/6, n = t2%6;
        float a0 = 0.f, a3 = 0.f;
        #pragma unroll
        for (int k = 0; k < 6; ++k) {
            a0 = fmaf(b2f(Ebuf[m*56 + 6  + k]), CTf[864 + k*6 + n], a0);
            a3 = fmaf(b2f(Ebuf[m*56 + 18 + k]), CTf[900 + k*6 + n], a3);
        }
        Ebuf[((m % 36)*6 + n)*56 + m/36] = f2b(a0);     // E0 [(d1d2d3)][d0]
        TBt[((m % 6)*6 + n)*56 + m/6]    = f2b(a3);     // EBT [n=(d2d3)][k=(d0d1)]
    }
    __syncthreads();

    // ================= row 1 =================
    ACC0();
    MFMA_PHASE(1, 2, Tk6, 16);                               // P5: j=0 (T10)
    __syncthreads();
    SCATTER(2, 36, EbS[((m%36)*6 + n/6)*56 + (m/36)*6 + n%6] = f2b(v));  // P6
    {   // build T13 -> CTf overlay (rows 0..5, k-pads zero)
        const float* s = SITE(1,3);
        for (int idx = tid; idx < 288; idx += BLK) {
            int n = idx/48, k = idx%48;
            float v0 = 0.f;
            if (k < 36) {
                int g = (k/6)*216 + (k%6) + n*6;
                float a = s[g], c = s[g+1296];
                v0 = xs[14] * a + xs[15] * c;
            }
            ((unsigned short*)CTf)[n*56 + k] = f2b(v0);
        }
    }
    __syncthreads();
    ACC0();
    MFMA_PHASE(3, 2, TA, 56);                                // P7: j=1 (T11)
    __syncthreads();
    SCATTER(2, 36, EbS[((m%36)*6 + n/6)*56 + (m/36)*6 + n%6] = f2b(v));  // P8
    {   // build T12 -> TA (T11 dead)
        const float* s = SITE(1,2);
        for (int idx = tid; idx < 1728; idx += BLK) {
            int n = idx/48, k = idx%48;
            float v0 = 0.f;
            if (k < 36) {
                int g = (k/6)*216 + (k%6) + (n/6)*6 + (n%6)*36;
                float a = s[g], c = s[g+1296];
                v0 = xs[12] * a + xs[13] * c;
            }
            TA[n*56 + k] = f2b(v0);
        }
    }
    __syncthreads();
    ACC0();
    MFMA_PHASE(3, 2, TA, 56);                                // P9: j=2 (T12)
    __syncthreads();
    SCATTER(2, 36, EbS[((m%36)*6 + n/6)*56 + (m/36)*6 + n%6] = f2b(v));  // P10
    {   // build T21 -> TA (T12 dead)
        const float* s = SITE(2,1);
        for (int idx = tid; idx < 1728; idx += BLK) {
            int n = idx/48, k = idx%48;
            float v0 = 0.f;
            if (k < 36) {
                int g = (k/6)*216 + (k%6) + (n/6)*6 + (n%6)*36;
                float a = s[g], c = s[g+1296];
                v0 = xs[18] * a + xs[19] * c;
            }
            TA[n*56 + k] = f2b(v0);
        }
    }
    __syncthreads();
    ACC0();
    MFMA_PHASE(3, 1, (unsigned short*)CTf, 56);              // P11: j=3 (T13)
    __syncthreads();
    SCATTER(1, 6, EbS[((m%36)*6 + n)*56 + m/36] = f2b(v));   // P12: env_top
    {   // build NT -> CTf overlay (T13 dead)
        const float* s = SITE(2,3);
        for (int idx = tid; idx < 288; idx += BLK) {
            int n = idx/48, k = idx%48;
            float v0 = 0.f;
            if (k < 36) {
                int g = (k/6)*216 + (k%6)*6 + n;
                float a = s[g], c = s[g+1296];
                v0 = xs[22] * a + xs[23] * c;
            }
            ((unsigned short*)CTf)[n*56 + k] = f2b(v0);
        }
    }
    __syncthreads();

    // ================= row 2 =================
    ACC0();
    MFMA_PHASE(1, 2, (Tk6 + 576), 16);                       // P13: j=0 (T20)
    __syncthreads();
    SCATTER(2, 36, EbS[((m%36)*6 + n/6)*56 + (m/36)*6 + n%6] = f2b(v));  // P14
    __syncthreads();
    ACC0();
    MFMA_PHASE(3, 2, TA, 56);                                // P15: j=1 (T21)
    __syncthreads();
    SCATTER(2, 36, EbS[((m/6)*6 + n%6)*56 + (m%6)*6 + n/6] = f2b(v));    // P16
    __syncthreads();
    ACC0();
    MFMA_PHASE(3, 2, TBt, 56);                               // P17: R = S_pre x EB
    __syncthreads();
    SCATTER(2, 36, EbS[((m/36)*36 + (m%6)*6 + n/6)*56 + ((m/6)%6)*6 + n%6] = f2b(v)); // P18
    __syncthreads();
    ACC0();
    MFMA_PHASE(3, 1, (unsigned short*)CTf, 56);              // P19a: T1 (NT)
    __syncthreads();   // all Ebuf frag reads done before T1 overlays it
    SCATTER(1, 6, T1S[m*6 + n] = v);                         // P19b
    __syncthreads();

    // ---- P20: out[o] = sum T1 * (x20*C0 + x21*C1), pepsc read once -------
    float part[10];
    #pragma unroll
    for (int o = 0; o < 10; ++o) part[o] = 0.f;
    {
        const float* T1p = (const float*)Ebuf;
        for (int c = tid; c < 1296; c += BLK) {
            int u2 = c / 216, r2 = (c / 36) % 6, d2 = (c / 6) % 6, r1 = c % 6;
            int e6 = u2*216 + r1*36 + d2*6 + r2;
            float t1 = T1p[e6];
            #pragma unroll
            for (int o = 0; o < 10; ++o) {
                float c0 = pepsc[o * 1296 + c];
                float c1 = pepsc[(10 + o) * 1296 + c];
                part[o] = fmaf(t1, xs[20] * c0 + xs[21] * c1, part[o]);
            }
        }
    }
    #pragma unroll
    for (int off = 32; off >= 1; off >>= 1)
        #pragma unroll
        for (int o = 0; o < 10; ++o)
            part[o] += __shfl_down(part[o], off, 64);
    if (lid == 0) {
        #pragma unroll
        for (int o = 0; o < 10; ++o) red[wid * 10 + o] = part[o];
    }
    __syncthreads();
    if (tid < 10)
        red[40 + tid] = red[tid] + red[10 + tid] + red[20 + tid] + red[30 + tid];
    __syncthreads();
    if (tid == 0) {
        float n2 = 0.f;
        #pragma unroll
        for (int o = 0; o < 10; ++o) n2 += red[40 + o] * red[40 + o];
        red[50] = 1.0f / sqrtf(n2);
    }
    __syncthreads();
    if (tid < 10) out[b0 * 10 + tid] = red[40 + tid] * red[50];
}

extern "C" void kernel_launch(void* const* d_in, const int* in_sizes, int n_in,
                              void* d_out, int out_size, void* d_ws, size_t ws_size,
                              hipStream_t stream) {
    const float* inputs = (const float*)d_in[0];   // (B,4,4,2) f32
    const float* peps   = (const float*)d_in[1];   // (4,4,2,6,6,6,6) f32
    const float* pepsc  = (const float*)d_in[2];   // (2,10,6,6,6,6) f32
    float* outp = (float*)d_out;                   // (B,10) f32
    const int B = in_sizes[0] / 32;
    peps_fused<<<dim3(B), dim3(BLK), 0, stream>>>(inputs, peps, pepsc, outp);
}